// Round 10
// baseline (1424.557 us; speedup 1.0000x reference)
//
#include <hip/hip_runtime.h>
#include <hip/hip_bf16.h>
#include <math.h>

#define N_TOT 400000
#define D_    256
#define B_    16384

typedef __attribute__((ext_vector_type(8))) short bf16x8;   // 8 bf16 in 4 VGPRs
typedef __attribute__((ext_vector_type(4))) float f32x4;

__device__ __forceinline__ ushort f2bf(float v) {
    unsigned int b = __float_as_uint(v);
    b += 0x7FFFu + ((b >> 16) & 1u);          // RNE
    return (ushort)(b >> 16);
}
__device__ __forceinline__ float bf2f(ushort h) {
    return __uint_as_float(((unsigned int)h) << 16);
}
__device__ __forceinline__ float sigm(float v)      { return 1.f / (1.f + __expf(-v)); }
__device__ __forceinline__ float tanh_fast(float v) { return 1.f - 2.f / (__expf(2.f * v) + 1.f); }

// ---------------------------------------------------------------------------
// Segment starts via binary search on sorted batch (int32 or int64 layouts).
// ---------------------------------------------------------------------------
__global__ void seg_starts_kernel(const int* __restrict__ batch,
                                  int* __restrict__ start) {
    int b = blockIdx.x * blockDim.x + threadIdx.x;
    if (b > B_) return;
    if (b == B_) { start[B_] = N_TOT; return; }
    const bool w64 = (batch[N_TOT - 1] == 0);   // int64 => high word of last elem = 0
    int lo = 0, hi = N_TOT;
    while (lo < hi) {
        int mid = (lo + hi) >> 1;
        int v = w64 ? batch[2 * mid] : batch[mid];
        if (v < b) lo = mid + 1; else hi = mid;
    }
    start[b] = lo;
}

// ---------------------------------------------------------------------------
// Weight conversion: W[rows][K] f32 -> W3[rows][3K] bf16 as [hi | hi | lo].
// Paired with activations stored [hi | lo | hi], one K'=3K GEMM computes
// ah*wh + al*wh + ah*wl ~= fp32 product (dropped al*wl ~ 2^-16 relative).
// ---------------------------------------------------------------------------
__global__ __launch_bounds__(256) void conv_w3_kernel(
    const float* __restrict__ W, ushort* __restrict__ W3,
    int total, int K, int ksh) {
    int i = blockIdx.x * 256 + threadIdx.x;
    if (i >= total) return;
    int n = i >> ksh;
    int k = i & (K - 1);
    float v = W[i];
    ushort hi = f2bf(v);
    ushort lo = f2bf(v - bf2f(hi));
    size_t base = (size_t)n * 3 * K + k;
    W3[base]         = hi;
    W3[base + K]     = hi;
    W3[base + 2 * K] = lo;
}

// ---------------------------------------------------------------------------
// Fused LSTM cell, bf16 MFMA (16x16x32), hi/lo split for ~fp32 accuracy.
//   gates[b][n] = sum_k' A'[b][k'] * W'[n][k']   (phase0: qs3/Wih3 K'=1536,
//                                                 phase1: h3/Whh3  K'=768)
// Block tile: 128 rows x (4 gates x 32 d-cols). 4 waves, each 64x64.
// Epilogue recombines gates across waves via LDS, applies activations,
// updates c, emits h3 = [hi | lo | hi].
// ---------------------------------------------------------------------------
#define LDK 72   // padded k-stride (elems): row stride 144B -> 2-way banks (free)

__global__ __launch_bounds__(256) void lstm_mfma_kernel(
    const ushort* __restrict__ qs3,   // [B,1536]
    const ushort* __restrict__ h3i,   // [B,768]
    const ushort* __restrict__ wih3,  // [1024,1536]
    const ushort* __restrict__ whh3,  // [1024,768]
    const float* __restrict__ b_ih,
    const float* __restrict__ b_hh,
    float* __restrict__ c_st,         // [B,256]
    ushort* __restrict__ h3o)         // [B,768]
{
    __shared__ ushort As[128 * LDK];  // 18 KB
    __shared__ ushort Ws[128 * LDK];  // 18 KB

    const int tid  = threadIdx.x;
    const int lane = tid & 63;
    const int wm = (tid >> 6) >> 1, wn = (tid >> 6) & 1;
    const int r0 = (int)(blockIdx.x >> 3) * 128;
    const int c0 = (int)(blockIdx.x & 7) * 32;
    const int l15 = lane & 15, lg = lane >> 4;

    f32x4 acc[4][4];
    #pragma unroll
    for (int mi = 0; mi < 4; ++mi)
        #pragma unroll
        for (int ni = 0; ni < 4; ++ni)
            acc[mi][ni] = (f32x4){0.f, 0.f, 0.f, 0.f};

    #pragma unroll
    for (int phase = 0; phase < 2; ++phase) {
        const ushort* Aptr = phase ? h3i : qs3;
        const ushort* Wptr = phase ? whh3 : wih3;
        const int Kp = phase ? 768 : 1536;

        for (int k0 = 0; k0 < Kp; k0 += 64) {
            __syncthreads();
            // stage A tile [128][64] and W tile [128][64] (W rows: gate*256+c0+d)
            #pragma unroll
            for (int i = 0; i < 4; ++i) {
                int ch = tid + i * 256;           // 0..1023
                int row = ch >> 3, kc = ch & 7;
                uint4 av = *(const uint4*)&Aptr[(size_t)(r0 + row) * Kp + k0 + kc * 8];
                *(uint4*)&As[row * LDK + kc * 8] = av;
                int wrow = ((row >> 5) << 8) + c0 + (row & 31);
                uint4 wv = *(const uint4*)&Wptr[(size_t)wrow * Kp + k0 + kc * 8];
                *(uint4*)&Ws[row * LDK + kc * 8] = wv;
            }
            __syncthreads();

            #pragma unroll
            for (int kk = 0; kk < 2; ++kk) {
                bf16x8 af[4], bfr[4];
                #pragma unroll
                for (int mi = 0; mi < 4; ++mi)
                    af[mi] = *(const bf16x8*)&As[(wm * 64 + mi * 16 + l15) * LDK + kk * 32 + lg * 8];
                #pragma unroll
                for (int ni = 0; ni < 4; ++ni)
                    bfr[ni] = *(const bf16x8*)&Ws[(wn * 64 + ni * 16 + l15) * LDK + kk * 32 + lg * 8];
                #pragma unroll
                for (int mi = 0; mi < 4; ++mi)
                    #pragma unroll
                    for (int ni = 0; ni < 4; ++ni)
                        acc[mi][ni] = __builtin_amdgcn_mfma_f32_16x16x32_bf16(
                            af[mi], bfr[ni], acc[mi][ni], 0, 0, 0);
            }
        }
    }

    // ---- epilogue: cross-wave gate recombine via LDS (reuse As as 16KB f32) ----
    float* L = (float*)As;            // [32][128]: rows = {wm=0:16, wm=1:16}, cols = 4 gates x 32 d
    const int fr = lg << 2;
    #pragma unroll
    for (int mi = 0; mi < 4; ++mi) {
        __syncthreads();
        #pragma unroll
        for (int ni = 0; ni < 4; ++ni) {
            #pragma unroll
            for (int r = 0; r < 4; ++r)
                L[(wm * 16 + fr + r) * 128 + wn * 64 + ni * 16 + l15] = acc[mi][ni][r];
        }
        __syncthreads();

        const int lr = tid >> 3;              // 0..31
        const int d0 = (tid & 7) * 4;         // 0..28
        const int brow = ((lr >> 4) << 6) + mi * 16 + (lr & 15);
        const size_t gb = (size_t)(r0 + brow);

        float4 fvi = *(const float4*)&L[lr * 128 + d0];
        float4 fvf = *(const float4*)&L[lr * 128 + 32 + d0];
        float4 fvg = *(const float4*)&L[lr * 128 + 64 + d0];
        float4 fvo = *(const float4*)&L[lr * 128 + 96 + d0];
        float gi[4] = {fvi.x, fvi.y, fvi.z, fvi.w};
        float gf[4] = {fvf.x, fvf.y, fvf.z, fvf.w};
        float gg[4] = {fvg.x, fvg.y, fvg.z, fvg.w};
        float go[4] = {fvo.x, fvo.y, fvo.z, fvo.w};
        float4 cold = *(const float4*)&c_st[gb * 256 + c0 + d0];
        float co[4] = {cold.x, cold.y, cold.z, cold.w};

        float cn[4];
        ushort hhi[4], hlo[4];
        #pragma unroll
        for (int j = 0; j < 4; ++j) {
            int d = c0 + d0 + j;
            float I = sigm(gi[j] + b_ih[d]       + b_hh[d]);
            float F = sigm(gf[j] + b_ih[256 + d] + b_hh[256 + d]);
            float G = tanh_fast(gg[j] + b_ih[512 + d] + b_hh[512 + d]);
            float O = sigm(go[j] + b_ih[768 + d] + b_hh[768 + d]);
            cn[j] = F * co[j] + I * G;
            float hv = O * tanh_fast(cn[j]);
            hhi[j] = f2bf(hv);
            hlo[j] = f2bf(hv - bf2f(hhi[j]));
        }
        *(float4*)&c_st[gb * 256 + c0 + d0] = make_float4(cn[0], cn[1], cn[2], cn[3]);
        ushort4 h4 = make_ushort4(hhi[0], hhi[1], hhi[2], hhi[3]);
        ushort4 l4 = make_ushort4(hlo[0], hlo[1], hlo[2], hlo[3]);
        *(ushort4*)&h3o[gb * 768 + c0 + d0]       = h4;   // hi
        *(ushort4*)&h3o[gb * 768 + 256 + c0 + d0] = l4;   // lo
        *(ushort4*)&h3o[gb * 768 + 512 + c0 + d0] = h4;   // hi (3rd pass)
    }
}

// ---------------------------------------------------------------------------
// Per-graph attention pooling, one workgroup per graph.
// x rows cached in LDS during the dot pass (cap 48; mean len 24.4) so x is
// read from HBM once. Dots/weights in LDS for len<=256; global spill beyond.
// Emits q_star fp32 to d_out and [hi|lo|hi] bf16 to qs3 for the next LSTM.
// ---------------------------------------------------------------------------
#define XCAP 48

__global__ __launch_bounds__(256) void attn_pool_kernel(
    const float* __restrict__ x,       // [N,256]
    const ushort* __restrict__ h3,     // [B,768]  q = hi+lo
    const int* __restrict__ start,     // [B+1]
    float* __restrict__ g_dot,         // [N] spill scratch
    float* __restrict__ out,           // [B,512] f32 (d_out)
    ushort* __restrict__ qs3)          // [B,1536]
{
    __shared__ float x_sh[XCAP * 256]; // 48 KB
    __shared__ float q_sh[256];
    __shared__ float dot_sh[256];
    __shared__ float red[8];

    const int b = blockIdx.x;
    const int tid = threadIdx.x;
    const int lane = tid & 63, wid = tid >> 6;
    const int s = start[b];
    const int len = start[b + 1] - s;
    const bool small = (len <= 256);

    q_sh[tid] = bf2f(h3[(size_t)b * 768 + tid]) + bf2f(h3[(size_t)b * 768 + 256 + tid]);
    __syncthreads();

    // pass 1: one wave per node -- load row, cache to LDS, dot, track max
    float4 q4 = *(const float4*)&q_sh[lane * 4];
    float wmax = -INFINITY;
    for (int idx = wid; idx < len; idx += 4) {
        size_t n = (size_t)(s + idx);
        float4 x4 = *(const float4*)&x[n * 256 + lane * 4];
        if (idx < XCAP) *(float4*)&x_sh[idx * 256 + lane * 4] = x4;
        float p = x4.x * q4.x + x4.y * q4.y + x4.z * q4.z + x4.w * q4.w;
        #pragma unroll
        for (int m = 1; m < 64; m <<= 1) p += __shfl_xor(p, m);
        wmax = fmaxf(wmax, p);
        if (lane == 0) { if (small) dot_sh[idx] = p; else g_dot[n] = p; }
    }
    if (lane == 0) red[wid] = wmax;
    __syncthreads();
    const float mx = fmaxf(fmaxf(red[0], red[1]), fmaxf(red[2], red[3]));

    // pass 2: z = sum exp(dot - mx); small path overwrites dot_sh with e
    float zt = 0.f;
    if (small) {
        if (tid < len) { float e = __expf(dot_sh[tid] - mx); dot_sh[tid] = e; zt = e; }
    } else {
        for (int i = tid; i < len; i += 256) zt += __expf(g_dot[s + i] - mx);
    }
    #pragma unroll
    for (int m = 1; m < 64; m <<= 1) zt += __shfl_xor(zt, m);
    if (lane == 0) red[4 + wid] = zt;
    __syncthreads();
    const float inv = 1.f / ((red[4] + red[5] + red[6] + red[7]) + 1e-10f);

    // pass 3: readout[d] = sum_n w_n x[n][d]; thread owns column tid
    float acc = 0.f;
    if (small) {
        for (int i = 0; i < len; ++i) {
            float xv = (i < XCAP) ? x_sh[i * 256 + tid]
                                  : x[(size_t)(s + i) * 256 + tid];
            acc += dot_sh[i] * xv;
        }
        acc *= inv;
    } else {
        for (int ch = 0; ch < len; ch += 256) {
            int cnt = min(256, len - ch);
            __syncthreads();
            if (tid < cnt) dot_sh[tid] = __expf(g_dot[s + ch + tid] - mx) * inv;
            __syncthreads();
            for (int i = 0; i < cnt; ++i) {
                int gi2 = ch + i;
                float xv = (gi2 < XCAP) ? x_sh[gi2 * 256 + tid]
                                        : x[(size_t)(s + gi2) * 256 + tid];
                acc += dot_sh[i] * xv;
            }
        }
    }

    // write q_star fp32 and bf16 [hi|lo|hi]
    out[(size_t)b * 512 + tid]       = q_sh[tid];
    out[(size_t)b * 512 + 256 + tid] = acc;

    size_t base = (size_t)b * 1536;
    ushort qh = f2bf(q_sh[tid]);
    ushort ql = f2bf(q_sh[tid] - bf2f(qh));
    qs3[base + tid]        = qh;
    qs3[base + 512 + tid]  = ql;
    qs3[base + 1024 + tid] = qh;
    ushort rh = f2bf(acc);
    ushort rl = f2bf(acc - bf2f(rh));
    qs3[base + 256 + tid]  = rh;
    qs3[base + 768 + tid]  = rl;
    qs3[base + 1280 + tid] = rh;
}

// ---------------------------------------------------------------------------
extern "C" void kernel_launch(void* const* d_in, const int* in_sizes, int n_in,
                              void* d_out, int out_size, void* d_ws, size_t ws_size,
                              hipStream_t stream) {
    const float* x     = (const float*)d_in[0];
    const int*   batch = (const int*)d_in[1];
    const float* W_ih  = (const float*)d_in[2];
    const float* W_hh  = (const float*)d_in[3];
    const float* b_ih  = (const float*)d_in[4];
    const float* b_hh  = (const float*)d_in[5];
    float* out = (float*)d_out;

    // workspace layout (~118 MB)
    float*  c_st = (float*)d_ws;                               // [B,256] f32
    ushort* h3a  = (ushort*)(c_st + (size_t)B_ * 256);         // [B,768]
    ushort* h3b  = h3a + (size_t)B_ * 768;                     // [B,768]
    ushort* qs3  = h3b + (size_t)B_ * 768;                     // [B,1536]
    ushort* wih3 = qs3 + (size_t)B_ * 1536;                    // [1024,1536]
    ushort* whh3 = wih3 + (size_t)1024 * 1536;                 // [1024,768]
    float*  gdot = (float*)(whh3 + (size_t)1024 * 768);        // [N]
    int*    strt = (int*)(gdot + N_TOT);                       // [B+1]

    hipMemsetAsync(c_st, 0, (size_t)B_ * 256 * sizeof(float), stream);
    hipMemsetAsync(h3a,  0, (size_t)B_ * 768 * sizeof(ushort), stream);
    hipMemsetAsync(qs3,  0, (size_t)B_ * 1536 * sizeof(ushort), stream);

    seg_starts_kernel<<<(B_ + 256) / 256, 256, 0, stream>>>(batch, strt);
    conv_w3_kernel<<<(1024 * 512) / 256, 256, 0, stream>>>(W_ih, wih3, 1024 * 512, 512, 9);
    conv_w3_kernel<<<(1024 * 256) / 256, 256, 0, stream>>>(W_hh, whh3, 1024 * 256, 256, 8);

    ushort* hin = h3a;
    ushort* hout = h3b;
    for (int step = 0; step < 3; ++step) {
        lstm_mfma_kernel<<<(B_ / 128) * 8, 256, 0, stream>>>(
            qs3, hin, wih3, whh3, b_ih, b_hh, c_st, hout);
        attn_pool_kernel<<<B_, 256, 0, stream>>>(x, hout, strt, gdot, out, qs3);
        ushort* t = hin; hin = hout; hout = t;
    }
}